// Round 8
// baseline (3024.618 us; speedup 1.0000x reference)
//
#include <hip/hip_runtime.h>

typedef _Float16 h8 __attribute__((ext_vector_type(8)));
typedef float f32x4 __attribute__((ext_vector_type(4)));

#define NTHREADS 1024
#define ROWS 16
#define NBLK 256   // 4096 tokens / 16 rows

// LDS layout (bytes):
//   bufA : 16x1024 fp16 swizzled   at      0  (32768)
//   bufB : 16x1024 fp16 swizzled   at  32768  (32768)   (also: layer3 reduce scratch)
//   Yf   : 16x128  fp32 linear     at  65536  ( 8192)   (init only)
//   Yh   : 16x128  fp16 swizzled   at  73728  ( 4096)
#define SMEM_BYTES 77824

__device__ __forceinline__ float fast_tanh(float x) {
    float e = __expf(2.0f * x);
    return 1.0f - 2.0f / (e + 1.0f);
}

// ---------------- weight pack kernels (identical to round 7) ----------------
// Packed for 16 waves x 64 cols: fragment idx = ((w*NK + kk)*4 + ct)*64 + lane
//   holds W[w*64 + ct*16 + (lane&15)][kk*32 + (lane>>4)*8 + j], j=0..7
template<int K>
__global__ void __launch_bounds__(256) pack_kernel(const float* __restrict__ src,
                                                   _Float16* __restrict__ dst, int nfrag) {
    constexpr int NK = K / 32;
    int idx = blockIdx.x * 256 + threadIdx.x;
    if (idx >= nfrag) return;
    int lane = idx & 63;
    int ct   = (idx >> 6) & 3;
    int kk   = (idx >> 8) % NK;
    int w    = idx / (256 * NK);
    int col  = w * 64 + ct * 16 + (lane & 15);
    int kb   = kk * 32 + (lane >> 4) * 8;
    const float* s = src + (size_t)col * K + kb;
    f32x4 v0 = *(const f32x4*)s;
    f32x4 v1 = *(const f32x4*)(s + 4);
    h8 h;
    h[0]=(_Float16)v0[0]; h[1]=(_Float16)v0[1]; h[2]=(_Float16)v0[2]; h[3]=(_Float16)v0[3];
    h[4]=(_Float16)v1[0]; h[5]=(_Float16)v1[1]; h[6]=(_Float16)v1[2]; h[7]=(_Float16)v1[3];
    *(h8*)(dst + (size_t)idx * 8) = h;
}

// W3 pack (out_cols=128, K=1024): idx = (w*32 + kk)*64 + lane  (col-groups 0..7)
__global__ void __launch_bounds__(256) pack3_kernel(const float* __restrict__ src,
                                                    _Float16* __restrict__ dst, int nfrag) {
    int idx = blockIdx.x * 256 + threadIdx.x;
    if (idx >= nfrag) return;
    int lane = idx & 63;
    int kk   = (idx >> 6) & 31;
    int w    = idx >> 11;
    int col  = w * 16 + (lane & 15);
    int kb   = kk * 32 + (lane >> 4) * 8;
    const float* s = src + (size_t)col * 1024 + kb;
    f32x4 v0 = *(const f32x4*)s;
    f32x4 v1 = *(const f32x4*)(s + 4);
    h8 h;
    h[0]=(_Float16)v0[0]; h[1]=(_Float16)v0[1]; h[2]=(_Float16)v0[2]; h[3]=(_Float16)v0[3];
    h[4]=(_Float16)v1[0]; h[5]=(_Float16)v1[1]; h[6]=(_Float16)v1[2]; h[7]=(_Float16)v1[3];
    *(h8*)(dst + (size_t)idx * 8) = h;
}

// ---------------- fused MLP layer (M=16, 16 waves x 64 cols) ----------------
// dst[16][1024] = tanh(src[16][K] @ W^T + bias)
// NK==4  : full unroll, all loads issued upfront (one latency).
// NK>=8  : depth-3 prefetch ring with 4 static B sets (16 VGPR each).
template<int K>
__device__ __forceinline__ void mlp_layer(const char* __restrict__ src, char* __restrict__ dst,
                                          const _Float16* __restrict__ Wp,
                                          const float* __restrict__ bias,
                                          int w, int l15, int lhi, int lane)
{
    constexpr int NK = K / 32;
    const int colbase = w * 64;
    const _Float16* wb = Wp + (size_t)w * NK * 2048 + lane * 8;

    f32x4 acc[4];
#pragma unroll
    for (int ct = 0; ct < 4; ++ct) {
        float bv = bias[colbase + ct * 16 + l15];
        f32x4 a; a[0] = bv; a[1] = bv; a[2] = bv; a[3] = bv;
        acc[ct] = a;
    }

    auto loadB = [&](h8* b, int kk) {
#pragma unroll
        for (int ct = 0; ct < 4; ++ct)
            b[ct] = *(const h8*)(wb + (size_t)kk * 2048 + ct * 512);
    };
    auto loadA = [&](h8& a, int kk) {
        int byte = (l15 * (2 * K) + kk * 64 + lhi * 16) ^ ((l15 & 7) << 4);
        a = *(const h8*)(src + byte);
    };
    auto mfma4 = [&](h8& a, h8* b) {
        __builtin_amdgcn_s_setprio(1);
#pragma unroll
        for (int ct = 0; ct < 4; ++ct)
            acc[ct] = __builtin_amdgcn_mfma_f32_16x16x32_f16(a, b[ct], acc[ct], 0, 0, 0);
        __builtin_amdgcn_s_setprio(0);
    };

    if constexpr (NK == 4) {
        // ---- full unroll: issue everything, then compute ----
        h8 B[16], A[4];
#pragma unroll
        for (int kk = 0; kk < 4; ++kk)
            loadB(&B[kk * 4], kk);
#pragma unroll
        for (int kk = 0; kk < 4; ++kk)
            loadA(A[kk], kk);
        __builtin_amdgcn_s_setprio(1);
#pragma unroll
        for (int kk = 0; kk < 4; ++kk)
#pragma unroll
            for (int ct = 0; ct < 4; ++ct)
                acc[ct] = __builtin_amdgcn_mfma_f32_16x16x32_f16(A[kk], B[kk * 4 + ct], acc[ct], 0, 0, 0);
        __builtin_amdgcn_s_setprio(0);
    } else {
        static_assert(NK % 4 == 0, "NK multiple of 4");
        h8 b0[4], b1[4], b2[4], b3r[4], a0, a1;
        loadB(b0, 0); loadB(b1, 1); loadB(b2, 2); loadA(a0, 0);
#pragma unroll 1
        for (int kk2 = 0; kk2 < NK / 4 - 1; ++kk2) {
            const int k = 4 * kk2;
            loadA(a1, k + 1); loadB(b3r, k + 3); mfma4(a0, b0);
            loadA(a0, k + 2); loadB(b0, k + 4);  mfma4(a1, b1);
            loadA(a1, k + 3); loadB(b1, k + 5);  mfma4(a0, b2);
            loadA(a0, k + 4); loadB(b2, k + 6);  mfma4(a1, b3r);
        }
        {
            const int k = NK - 4;
            loadA(a1, k + 1); loadB(b3r, k + 3); mfma4(a0, b0);
            loadA(a0, k + 2); mfma4(a1, b1);
            loadA(a1, k + 3); mfma4(a0, b2);
            mfma4(a1, b3r);
        }
    }

#pragma unroll
    for (int ct = 0; ct < 4; ++ct)
#pragma unroll
        for (int j = 0; j < 4; ++j) {
            int row = lhi * 4 + j;
            int g = colbase + ct * 16 + l15;
            float v = fast_tanh(acc[ct][j]);
            int byte = ((row * 1024 + g) * 2) ^ ((row & 7) << 4);
            *(_Float16*)(dst + byte) = (_Float16)v;
        }
}

__global__ void
__attribute__((amdgpu_flat_work_group_size(NTHREADS, NTHREADS)))
node_kernel(const float* __restrict__ y0,
            const float* __restrict__ tarr,
            const float* __restrict__ W_aug,
            const float* __restrict__ b_aug,
            const float* __restrict__ b0,
            const float* __restrict__ b1,
            const float* __restrict__ b2,
            const float* __restrict__ b3,
            const _Float16* __restrict__ W0p,
            const _Float16* __restrict__ W1p,
            const _Float16* __restrict__ W2p,
            const _Float16* __restrict__ W3p,
            float* __restrict__ out)
{
    __shared__ __align__(16) char smem[SMEM_BYTES];
    char* bufA = smem;
    char* bufB = smem + 32768;
    float* red = (float*)(smem + 32768);   // layer3 reduce scratch (8 KB, aliases bufB)
    float* Yf  = (float*)(smem + 65536);
    char* Yh   = smem + 73728;

    const int tid  = threadIdx.x;
    const int lane = tid & 63;
    const int w    = tid >> 6;       // 0..15
    const int l15  = lane & 15;
    const int lhi  = lane >> 4;
    const int row0 = blockIdx.x * ROWS;

    const float dtv = tarr[1] - tarr[0];

    // ---- load y0 rows into Yf[:, 0:64] (16 rows x 64 cols = 1024 f32) ----
    if (tid < 256) {
        int idx = tid * 4;
        int r = idx >> 6;
        int c = idx & 63;
        f32x4 v = *(const f32x4*)(y0 + (size_t)(row0 + r) * 64 + c);
        *(f32x4*)(Yf + r * 128 + c) = v;
    }
    __syncthreads();

    // ---- augment: Yf[:, 64:128] = y0_row @ W_aug^T + b_aug (1 elem/thread) ----
    {
        int r = tid >> 6;
        int a0 = tid & 63;
        float acc = b_aug[a0];
        for (int d = 0; d < 64; ++d)
            acc += Yf[r * 128 + d] * W_aug[a0 * 64 + d];
        Yf[r * 128 + 64 + a0] = acc;
    }
    __syncthreads();

    // ---- initial fp16 mirror of Y (swizzled): 16x128 = 256 h8 ----
    if (tid < 256) {
        int r = tid >> 4;
        int c = (tid & 15) * 8;
        const float* p = Yf + r * 128 + c;
        h8 h;
#pragma unroll
        for (int j = 0; j < 8; ++j) h[j] = (_Float16)p[j];
        int byte = ((r * 128 + c) * 2) ^ ((r & 7) << 4);
        *(h8*)(Yh + byte) = h;
    }
    // thread-owned state (waves 0..7): col g = w*16+l15, rows lhi*4+j
    const int g = w * 16 + l15;
    f32x4 yreg;
    if (w < 8) {
#pragma unroll
        for (int j = 0; j < 4; ++j)
            yreg[j] = Yf[(lhi * 4 + j) * 128 + g];
    }
    __syncthreads();

    // layer-3: all 16 waves participate. Wave w covers col-group (w&7), kk range [(w>>3)*16, +16)
    const _Float16* wb3 = W3p + (size_t)(w & 7) * 32 * 512 + lane * 8;
    const int kk0 = (w >> 3) * 16;
    const float b3v = (w < 8) ? b3[g] : 0.0f;

    // ---- 31 Euler steps ----
    for (int s = 0; s < 31; ++s) {
        mlp_layer<128>(Yh, bufA, W0p, b0, w, l15, lhi, lane);
        __syncthreads();
        mlp_layer<1024>(bufA, bufB, W1p, b1, w, l15, lhi, lane);
        __syncthreads();
        mlp_layer<1024>(bufB, bufA, W2p, b2, w, l15, lhi, lane);
        __syncthreads();

        // layer 3: DY[16][128] = bufA @ W3^T + b3, K split across wave halves
        {
            f32x4 acc3;
            acc3[0]=b3v; acc3[1]=b3v; acc3[2]=b3v; acc3[3]=b3v;

            h8 c3E, c3O, x3E, x3O;
            auto loadB3 = [&](h8& b, int kk) {
                b = *(const h8*)(wb3 + (size_t)kk * 512);
            };
            auto loadA3 = [&](h8& a, int kk) {
                int byte = (l15 * 2048 + kk * 64 + lhi * 16) ^ ((l15 & 7) << 4);
                a = *(const h8*)(bufA + byte);
            };

            loadB3(c3E, kk0 + 0); loadA3(x3E, kk0 + 0);
#pragma unroll 1
            for (int kk2 = 0; kk2 < 7; ++kk2) {
                loadB3(c3O, kk0 + 2 * kk2 + 1); loadA3(x3O, kk0 + 2 * kk2 + 1);
                acc3 = __builtin_amdgcn_mfma_f32_16x16x32_f16(x3E, c3E, acc3, 0, 0, 0);
                loadB3(c3E, kk0 + 2 * kk2 + 2); loadA3(x3E, kk0 + 2 * kk2 + 2);
                acc3 = __builtin_amdgcn_mfma_f32_16x16x32_f16(x3O, c3O, acc3, 0, 0, 0);
            }
            loadB3(c3O, kk0 + 15); loadA3(x3O, kk0 + 15);
            acc3 = __builtin_amdgcn_mfma_f32_16x16x32_f16(x3E, c3E, acc3, 0, 0, 0);
            acc3 = __builtin_amdgcn_mfma_f32_16x16x32_f16(x3O, c3O, acc3, 0, 0, 0);

            // waves 8..15 publish partials (bufB is free here)
            if (w >= 8)
                *(f32x4*)(red + ((size_t)(w & 7) * 64 + lane) * 4) = acc3;
            __syncthreads();
            if (w < 8) {
                f32x4 part = *(const f32x4*)(red + ((size_t)w * 64 + lane) * 4);
#pragma unroll
                for (int j = 0; j < 4; ++j) {
                    int row = lhi * 4 + j;
                    float nv = yreg[j] + dtv * (acc3[j] + part[j]);
                    yreg[j] = nv;
                    int byte = ((row * 128 + g) * 2) ^ ((row & 7) << 4);
                    *(_Float16*)(Yh + byte) = (_Float16)nv;
                }
            }
        }
        __syncthreads();
    }

    // ---- output: out[token][0:64] from registers (cols 0..63 = waves 0..3) ----
    if (w < 4) {
#pragma unroll
        for (int j = 0; j < 4; ++j) {
            int row = lhi * 4 + j;
            out[(size_t)(row0 + row) * 64 + g] = yreg[j];
        }
    }
}

extern "C" void kernel_launch(void* const* d_in, const int* in_sizes, int n_in,
                              void* d_out, int out_size, void* d_ws, size_t ws_size,
                              hipStream_t stream)
{
    const float* y0    = (const float*)d_in[0];
    const float* tarr  = (const float*)d_in[1];
    const float* W_aug = (const float*)d_in[2];
    const float* b_aug = (const float*)d_in[3];
    const float* W0    = (const float*)d_in[4];
    const float* b0    = (const float*)d_in[5];
    const float* W1    = (const float*)d_in[6];
    const float* b1    = (const float*)d_in[7];
    const float* W2    = (const float*)d_in[8];
    const float* b2    = (const float*)d_in[9];
    const float* W3    = (const float*)d_in[10];
    const float* b3    = (const float*)d_in[11];

    _Float16* W0p = (_Float16*)d_ws;            // 1024*128  = 131072 halves
    _Float16* W1p = W0p + 131072;               // 1024*1024 = 1048576
    _Float16* W2p = W1p + 1048576;
    _Float16* W3p = W2p + 1048576;              // 128*1024  = 131072

    pack_kernel<128><<<16384 / 256, 256, 0, stream>>>(W0, W0p, 16384);
    pack_kernel<1024><<<131072 / 256, 256, 0, stream>>>(W1, W1p, 131072);
    pack_kernel<1024><<<131072 / 256, 256, 0, stream>>>(W2, W2p, 131072);
    pack3_kernel<<<16384 / 256, 256, 0, stream>>>(W3, W3p, 16384);

    node_kernel<<<NBLK, NTHREADS, 0, stream>>>(y0, tarr, W_aug, b_aug,
                                               b0, b1, b2, b3,
                                               W0p, W1p, W2p, W3p,
                                               (float*)d_out);
}

// Round 10
// 1451.653 us; speedup vs baseline: 2.0836x; 2.0836x over previous
//
#include <hip/hip_runtime.h>

typedef _Float16 h8 __attribute__((ext_vector_type(8)));
typedef float f32x4 __attribute__((ext_vector_type(4)));
typedef int  i4 __attribute__((ext_vector_type(4)));

#define NTHREADS 1024
#define ROWS 16
#define NBLK 256   // 4096 tokens / 16 rows

// LDS layout (bytes):
//   buf8A : 16x1024 int8 swizzled  at      0  (16384)  L0 out -> L1 in
//   buf8B : 16x1024 int8 swizzled  at  16384  (16384)  L1 out -> L2 in
//   bufF  : 16x1024 fp16 swizzled  at  32768  (32768)  L2 out -> L3 in
//   Yf    : 16x128  fp32 linear    at  65536  ( 8192)  (init only)
//   Yh    : 16x128  fp16 swizzled  at  73728  ( 4096)
#define SMEM_BYTES 77824

__device__ __forceinline__ float fast_tanh(float x) {
    float e = __expf(2.0f * x);
    return 1.0f - 2.0f / (e + 1.0f);
}

// ---------------- weight pack kernels ----------------
// fp16 pack (W0): fragment idx = ((w*NK + kk)*4 + ct)*64 + lane, 16B (h8) each
//   holds W[w*64 + ct*16 + (lane&15)][kk*32 + (lane>>4)*8 + j], j=0..7
template<int K>
__global__ void __launch_bounds__(256) pack_kernel(const float* __restrict__ src,
                                                   _Float16* __restrict__ dst, int nfrag) {
    constexpr int NK = K / 32;
    int idx = blockIdx.x * 256 + threadIdx.x;
    if (idx >= nfrag) return;
    int lane = idx & 63;
    int ct   = (idx >> 6) & 3;
    int kk   = (idx >> 8) % NK;
    int w    = idx / (256 * NK);
    int col  = w * 64 + ct * 16 + (lane & 15);
    int kb   = kk * 32 + (lane >> 4) * 8;
    const float* s = src + (size_t)col * K + kb;
    f32x4 v0 = *(const f32x4*)s;
    f32x4 v1 = *(const f32x4*)(s + 4);
    h8 h;
    h[0]=(_Float16)v0[0]; h[1]=(_Float16)v0[1]; h[2]=(_Float16)v0[2]; h[3]=(_Float16)v0[3];
    h[4]=(_Float16)v1[0]; h[5]=(_Float16)v1[1]; h[6]=(_Float16)v1[2]; h[7]=(_Float16)v1[3];
    *(h8*)(dst + (size_t)idx * 8) = h;
}

// int8 pack (W1/W2, K=1024): fragment idx = ((w*16 + kk)*4 + ct)*64 + lane, 16B each
//   holds round(W[w*64 + ct*16 + (lane&15)][kk*64 + (lane>>4)*16 + j] * 32*127), j=0..15
__global__ void __launch_bounds__(256) pack8_kernel(const float* __restrict__ src,
                                                    char* __restrict__ dst, int nfrag) {
    int idx = blockIdx.x * 256 + threadIdx.x;
    if (idx >= nfrag) return;
    int lane = idx & 63;
    int ct   = (idx >> 6) & 3;
    int kk   = (idx >> 8) & 15;
    int w    = idx >> 12;
    int col  = w * 64 + ct * 16 + (lane & 15);
    int kb   = kk * 64 + (lane >> 4) * 16;
    const float* s = src + (size_t)col * 1024 + kb;
    union { char q[16]; i4 v; } u;
#pragma unroll
    for (int j = 0; j < 16; ++j)
        u.q[j] = (char)__float2int_rn(s[j] * 4064.0f);   // 32*127
    *(i4*)(dst + (size_t)idx * 16) = u.v;
}

// W3 pack fp16 (out_cols=128, K=1024): idx = (w*32 + kk)*64 + lane  (col-groups 0..7)
__global__ void __launch_bounds__(256) pack3_kernel(const float* __restrict__ src,
                                                    _Float16* __restrict__ dst, int nfrag) {
    int idx = blockIdx.x * 256 + threadIdx.x;
    if (idx >= nfrag) return;
    int lane = idx & 63;
    int kk   = (idx >> 6) & 31;
    int w    = idx >> 11;
    int col  = w * 16 + (lane & 15);
    int kb   = kk * 32 + (lane >> 4) * 8;
    const float* s = src + (size_t)col * 1024 + kb;
    f32x4 v0 = *(const f32x4*)s;
    f32x4 v1 = *(const f32x4*)(s + 4);
    h8 h;
    h[0]=(_Float16)v0[0]; h[1]=(_Float16)v0[1]; h[2]=(_Float16)v0[2]; h[3]=(_Float16)v0[3];
    h[4]=(_Float16)v1[0]; h[5]=(_Float16)v1[1]; h[6]=(_Float16)v1[2]; h[7]=(_Float16)v1[3];
    *(h8*)(dst + (size_t)idx * 8) = h;
}

// ---------------- layer 0: fp16 x fp16 (K=128) -> int8 out ----------------
__device__ __forceinline__ void mlp0(const char* __restrict__ src, char* __restrict__ dst,
                                     const _Float16* __restrict__ Wp,
                                     const float* __restrict__ bias,
                                     int w, int l15, int lhi, int lane)
{
    constexpr int K = 128, NK = 4;
    const int colbase = w * 64;
    const _Float16* wb = Wp + (size_t)w * NK * 2048 + lane * 8;

    f32x4 acc[4];
#pragma unroll
    for (int ct = 0; ct < 4; ++ct) {
        float bv = bias[colbase + ct * 16 + l15];
        f32x4 a; a[0] = bv; a[1] = bv; a[2] = bv; a[3] = bv;
        acc[ct] = a;
    }

    h8 bE[4], bO[4], aE, aO;
    auto loadB = [&](h8* b, int kk) {
#pragma unroll
        for (int ct = 0; ct < 4; ++ct)
            b[ct] = *(const h8*)(wb + (size_t)kk * 2048 + ct * 512);
    };
    auto loadA = [&](h8& a, int kk) {
        int byte = (l15 * (2 * K) + kk * 64 + lhi * 16) ^ ((l15 & 7) << 4);
        a = *(const h8*)(src + byte);
    };
    auto mfma4 = [&](h8& a, h8* b) {
        __builtin_amdgcn_s_setprio(1);
#pragma unroll
        for (int ct = 0; ct < 4; ++ct)
            acc[ct] = __builtin_amdgcn_mfma_f32_16x16x32_f16(a, b[ct], acc[ct], 0, 0, 0);
        __builtin_amdgcn_s_setprio(0);
    };

    loadB(bE, 0); loadA(aE, 0);
    loadB(bO, 1); loadA(aO, 1);
    mfma4(aE, bE);
    loadB(bE, 2); loadA(aE, 2);
    mfma4(aO, bO);
    loadB(bO, 3); loadA(aO, 3);
    mfma4(aE, bE);
    mfma4(aO, bO);

#pragma unroll
    for (int ct = 0; ct < 4; ++ct)
#pragma unroll
        for (int j = 0; j < 4; ++j) {
            int row = lhi * 4 + j;
            int gc = colbase + ct * 16 + l15;
            int q = __float2int_rn(fast_tanh(acc[ct][j]) * 127.0f);
            int byte = (row * 1024 + gc) ^ ((row & 7) << 4);
            *(char*)(dst + byte) = (char)q;
        }
}

// ---------------- layers 1/2: int8 x int8 (K=1024, mfma_i32_16x16x64_i8) ----------------
template<bool OUT8>
__device__ __forceinline__ void mlp8(const char* __restrict__ src, char* __restrict__ dst,
                                     const char* __restrict__ Wq,
                                     const float* __restrict__ bias,
                                     int w, int l15, int lhi, int lane)
{
    const int colbase = w * 64;
    const char* wb = Wq + (size_t)w * 65536 + lane * 16;

    i4 acc[4];
#pragma unroll
    for (int ct = 0; ct < 4; ++ct) { i4 z; z[0]=0; z[1]=0; z[2]=0; z[3]=0; acc[ct] = z; }

    i4 bE[4], bO[4], aE, aO;
    auto loadB = [&](i4* b, int kk) {
#pragma unroll
        for (int ct = 0; ct < 4; ++ct)
            b[ct] = *(const i4*)(wb + (size_t)(kk * 4 + ct) * 1024);
    };
    auto loadA = [&](i4& a, int kk) {
        int byte = (l15 * 1024 + kk * 64 + lhi * 16) ^ ((l15 & 7) << 4);
        a = *(const i4*)(src + byte);
    };
    auto mfma4 = [&](i4& a, i4* b) {
        __builtin_amdgcn_s_setprio(1);
#pragma unroll
        for (int ct = 0; ct < 4; ++ct)
            acc[ct] = __builtin_amdgcn_mfma_i32_16x16x64_i8(a, b[ct], acc[ct], 0, 0, 0);
        __builtin_amdgcn_s_setprio(0);
    };

    // NK = 16 K-steps of 64; 2-deep ping-pong (round-7 proven shape)
    loadB(bE, 0); loadA(aE, 0);
#pragma unroll 1
    for (int kk2 = 0; kk2 < 7; ++kk2) {
        loadB(bO, 2 * kk2 + 1); loadA(aO, 2 * kk2 + 1);
        mfma4(aE, bE);
        loadB(bE, 2 * kk2 + 2); loadA(aE, 2 * kk2 + 2);
        mfma4(aO, bO);
    }
    loadB(bO, 15); loadA(aO, 15);
    mfma4(aE, bE);
    mfma4(aO, bO);

    const float DEQ = 1.0f / 516128.0f;   // 1/(32*127*127)
#pragma unroll
    for (int ct = 0; ct < 4; ++ct) {
        int gc = colbase + ct * 16 + l15;
        float bv = bias[gc];
#pragma unroll
        for (int j = 0; j < 4; ++j) {
            int row = lhi * 4 + j;
            float v = fast_tanh((float)acc[ct][j] * DEQ + bv);
            if constexpr (OUT8) {
                int q = __float2int_rn(v * 127.0f);
                int byte = (row * 1024 + gc) ^ ((row & 7) << 4);
                *(char*)(dst + byte) = (char)q;
            } else {
                int byte = ((row * 1024 + gc) * 2) ^ ((row & 7) << 4);
                *(_Float16*)(dst + byte) = (_Float16)v;
            }
        }
    }
}

__global__ void
__attribute__((amdgpu_flat_work_group_size(NTHREADS, NTHREADS)))
node_kernel(const float* __restrict__ y0,
            const float* __restrict__ tarr,
            const float* __restrict__ W_aug,
            const float* __restrict__ b_aug,
            const float* __restrict__ b0,
            const float* __restrict__ b1,
            const float* __restrict__ b2,
            const float* __restrict__ b3,
            const _Float16* __restrict__ W0p,
            const char* __restrict__ W1q,
            const char* __restrict__ W2q,
            const _Float16* __restrict__ W3p,
            float* __restrict__ out)
{
    __shared__ __align__(16) char smem[SMEM_BYTES];
    char* buf8A = smem;
    char* buf8B = smem + 16384;
    char* bufF  = smem + 32768;
    float* Yf   = (float*)(smem + 65536);
    char* Yh    = smem + 73728;

    const int tid  = threadIdx.x;
    const int lane = tid & 63;
    const int w    = tid >> 6;       // 0..15
    const int l15  = lane & 15;
    const int lhi  = lane >> 4;
    const int row0 = blockIdx.x * ROWS;

    const float dtv = tarr[1] - tarr[0];

    // ---- load y0 rows into Yf[:, 0:64] ----
    if (tid < 256) {
        int idx = tid * 4;
        int r = idx >> 6;
        int c = idx & 63;
        f32x4 v = *(const f32x4*)(y0 + (size_t)(row0 + r) * 64 + c);
        *(f32x4*)(Yf + r * 128 + c) = v;
    }
    __syncthreads();

    // ---- augment: Yf[:, 64:128] = y0_row @ W_aug^T + b_aug (1 elem/thread) ----
    {
        int r = tid >> 6;
        int a0 = tid & 63;
        float acc = b_aug[a0];
        for (int d = 0; d < 64; ++d)
            acc += Yf[r * 128 + d] * W_aug[a0 * 64 + d];
        Yf[r * 128 + 64 + a0] = acc;
    }
    __syncthreads();

    // ---- initial fp16 mirror of Y (swizzled) ----
    if (tid < 256) {
        int r = tid >> 4;
        int c = (tid & 15) * 8;
        const float* p = Yf + r * 128 + c;
        h8 h;
#pragma unroll
        for (int j = 0; j < 8; ++j) h[j] = (_Float16)p[j];
        int byte = ((r * 128 + c) * 2) ^ ((r & 7) << 4);
        *(h8*)(Yh + byte) = h;
    }
    // thread-owned state (waves 0..7): col g = w*16+l15, rows lhi*4+j
    const int g = w * 16 + l15;
    f32x4 yreg;
    if (w < 8) {
#pragma unroll
        for (int j = 0; j < 4; ++j)
            yreg[j] = Yf[(lhi * 4 + j) * 128 + g];
    }
    __syncthreads();

    const _Float16* wb3 = W3p + (size_t)w * 32 * 512 + lane * 8;
    const float b3v = (w < 8) ? b3[g] : 0.0f;

    // ---- 31 Euler steps ----
    for (int s = 0; s < 31; ++s) {
        mlp0(Yh, buf8A, W0p, b0, w, l15, lhi, lane);
        __syncthreads();
        mlp8<true >(buf8A, buf8B, W1q, b1, w, l15, lhi, lane);
        __syncthreads();
        mlp8<false>(buf8B, bufF,  W2q, b2, w, l15, lhi, lane);
        __syncthreads();

        // layer 3 (waves 0..7, fp16): DY[16][128] = bufF @ W3^T + b3 ; yreg += dt*DY
        if (w < 8) {
            f32x4 acc3;
            acc3[0]=b3v; acc3[1]=b3v; acc3[2]=b3v; acc3[3]=b3v;

            h8 c3E, c3O, x3E, x3O;
            auto loadB3 = [&](h8& b, int kk) {
                b = *(const h8*)(wb3 + (size_t)kk * 512);
            };
            auto loadA3 = [&](h8& a, int kk) {
                int byte = (l15 * 2048 + kk * 64 + lhi * 16) ^ ((l15 & 7) << 4);
                a = *(const h8*)(bufF + byte);
            };

            loadB3(c3E, 0); loadA3(x3E, 0);
#pragma unroll 1
            for (int kk2 = 0; kk2 < 15; ++kk2) {
                loadB3(c3O, 2 * kk2 + 1); loadA3(x3O, 2 * kk2 + 1);
                acc3 = __builtin_amdgcn_mfma_f32_16x16x32_f16(x3E, c3E, acc3, 0, 0, 0);
                loadB3(c3E, 2 * kk2 + 2); loadA3(x3E, 2 * kk2 + 2);
                acc3 = __builtin_amdgcn_mfma_f32_16x16x32_f16(x3O, c3O, acc3, 0, 0, 0);
            }
            loadB3(c3O, 31); loadA3(x3O, 31);
            acc3 = __builtin_amdgcn_mfma_f32_16x16x32_f16(x3E, c3E, acc3, 0, 0, 0);
            acc3 = __builtin_amdgcn_mfma_f32_16x16x32_f16(x3O, c3O, acc3, 0, 0, 0);

#pragma unroll
            for (int j = 0; j < 4; ++j) {
                int row = lhi * 4 + j;
                float nv = yreg[j] + dtv * acc3[j];
                yreg[j] = nv;
                int byte = ((row * 128 + g) * 2) ^ ((row & 7) << 4);
                *(_Float16*)(Yh + byte) = (_Float16)nv;
            }
        }
        __syncthreads();
    }

    // ---- output: out[token][0:64] from registers (cols 0..63 = waves 0..3) ----
    if (w < 4) {
#pragma unroll
        for (int j = 0; j < 4; ++j) {
            int row = lhi * 4 + j;
            out[(size_t)(row0 + row) * 64 + g] = yreg[j];
        }
    }
}

extern "C" void kernel_launch(void* const* d_in, const int* in_sizes, int n_in,
                              void* d_out, int out_size, void* d_ws, size_t ws_size,
                              hipStream_t stream)
{
    const float* y0    = (const float*)d_in[0];
    const float* tarr  = (const float*)d_in[1];
    const float* W_aug = (const float*)d_in[2];
    const float* b_aug = (const float*)d_in[3];
    const float* W0    = (const float*)d_in[4];
    const float* b0    = (const float*)d_in[5];
    const float* W1    = (const float*)d_in[6];
    const float* b1    = (const float*)d_in[7];
    const float* W2    = (const float*)d_in[8];
    const float* b2    = (const float*)d_in[9];
    const float* W3    = (const float*)d_in[10];
    const float* b3    = (const float*)d_in[11];

    // d_ws layout (bytes): W0p fp16 @0 (262144), W3p fp16 @262144 (262144),
    //                      W1q int8 @524288 (1048576), W2q int8 @1572864 (1048576)
    _Float16* W0p = (_Float16*)d_ws;
    _Float16* W3p = W0p + 131072;
    char* W1q = (char*)d_ws + 524288;
    char* W2q = W1q + 1048576;

    pack_kernel<128><<<16384 / 256, 256, 0, stream>>>(W0, W0p, 16384);
    pack8_kernel<<<65536 / 256, 256, 0, stream>>>(W1, W1q, 65536);
    pack8_kernel<<<65536 / 256, 256, 0, stream>>>(W2, W2q, 65536);
    pack3_kernel<<<16384 / 256, 256, 0, stream>>>(W3, W3p, 16384);

    node_kernel<<<NBLK, NTHREADS, 0, stream>>>(y0, tarr, W_aug, b_aug,
                                               b0, b1, b2, b3,
                                               W0p, W1q, W2q, W3p,
                                               (float*)d_out);
}